// Round 8
// baseline (92.445 us; speedup 1.0000x reference)
//
#include <hip/hip_runtime.h>
#include <math.h>

#define NTOK 16384
#define DIM  4096
#define NEXP 64
#define KS   4                // K-split factor
#define KSL  (DIM / KS)       // 1024 k per slice
#define NCH  (KSL / 32)       // 32 chunks of 32 per slice
#define BM   64               // tokens per block (4 waves x 16)

typedef __fp16 f16x8 __attribute__((ext_vector_type(8)));
typedef __fp16 f16x2 __attribute__((ext_vector_type(2)));
typedef float  f32x4 __attribute__((ext_vector_type(4)));

__device__ __forceinline__ void gl_lds16(const void* g, void* l) {
  __builtin_amdgcn_global_load_lds(
      (const __attribute__((address_space(1))) void*)g,
      (__attribute__((address_space(3))) void*)l, 16, 0, 0);
}

// ---- prep: split W (fp32) into 2 fp16 planes (RNE hi, RNE residual) ----
__global__ __launch_bounds__(256) void split_w(
    const float* __restrict__ W,
    __fp16* __restrict__ Wh,
    __fp16* __restrict__ Wl)
{
  const int i = blockIdx.x * 256 + threadIdx.x;   // grid covers 64*4096
  const float w = W[i];
  const __fp16 h = (__fp16)w;                     // RNE
  const float r = w - (float)h;                   // exact
  Wh[i] = h;
  Wl[i] = (__fp16)r;                              // RNE, residual ~2^-24|w|
}

// ---- phase 1: partial logits; 3-buffer LDS pipeline, counted vmcnt ----
__global__ __launch_bounds__(256, 3) void router_mfma(
    const float* __restrict__ tokens,
    const __fp16* __restrict__ Wh,
    const __fp16* __restrict__ Wl,
    float* __restrict__ partial)   // [KS][NTOK][NEXP]
{
  __shared__ float  As[3][BM * 32];     // 3 x 8 KB
  __shared__ __fp16 Bh[3][NEXP * 32];   // 3 x 4 KB
  __shared__ __fp16 Bl[3][NEXP * 32];   // 3 x 4 KB   -> 48 KB total

  const int tid  = threadIdx.x;
  const int wid  = tid >> 6;
  const int lane = tid & 63;
  const int rc   = lane & 15;           // A-row / B-col within 16
  const int q    = lane >> 4;           // k-group (0..3)
  const int s    = blockIdx.x & (KS - 1);
  const int rowbase = (blockIdx.x >> 2) * BM;     // block token base
  const int wrow    = rowbase + 16 * wid;         // this wave's token base
  const int kbase   = s * KSL;

  // ---- staging sources (pre-swizzled global addr, linear LDS dest: G21) ----
  const int a_tl = lane >> 3, a_j = lane & 7;
  const float* asrc0 = tokens + (size_t)(wrow + a_tl) * DIM + kbase
                       + ((a_j ^ a_tl) << 2);
  const float* asrc1 = asrc0 + (size_t)8 * DIM;
  const int b_el = lane >> 2, b_j = lane & 3;
  const size_t boff = (size_t)(16 * wid + b_el) * DIM + kbase
                      + ((b_j ^ (b_el & 3)) << 3);
  const __fp16* bsrc_h = Wh + boff;
  const __fp16* bsrc_l = Wl + boff;

#define STAGE(buf, c) {                                        \
    const int ko = (c) * 32;                                   \
    gl_lds16(asrc0 + ko,  &As[buf][(16 * wid) * 32]);          \
    gl_lds16(asrc1 + ko,  &As[buf][(16 * wid + 8) * 32]);      \
    gl_lds16(bsrc_h + ko, &Bh[buf][(16 * wid) * 32]);          \
    gl_lds16(bsrc_l + ko, &Bl[buf][(16 * wid) * 32]);          \
  }

  f32x4 acc0 = {0.f,0.f,0.f,0.f}, acc1 = {0.f,0.f,0.f,0.f};
  f32x4 acc2 = {0.f,0.f,0.f,0.f}, acc3 = {0.f,0.f,0.f,0.f};

  // read-side swizzled slots (constant per thread)
  const int sa0 = (2 * q) ^ (rc & 7), sa1 = (2 * q + 1) ^ (rc & 7);
  const int sb  = q ^ (rc & 3);
  const int arow = (16 * wid + rc) * 32;

#define COMP(buf) {                                                          \
    const float4 a0 = *(const float4*)(&As[buf][arow + sa0 * 4]);            \
    const float4 a1 = *(const float4*)(&As[buf][arow + sa1 * 4]);            \
    const f16x8 bh0 = *(const f16x8*)(&Bh[buf][( 0 + rc) * 32 + sb * 8]);    \
    const f16x8 bh1 = *(const f16x8*)(&Bh[buf][(16 + rc) * 32 + sb * 8]);    \
    const f16x8 bh2 = *(const f16x8*)(&Bh[buf][(32 + rc) * 32 + sb * 8]);    \
    const f16x8 bh3 = *(const f16x8*)(&Bh[buf][(48 + rc) * 32 + sb * 8]);    \
    const f16x8 bl0 = *(const f16x8*)(&Bl[buf][( 0 + rc) * 32 + sb * 8]);    \
    const f16x8 bl1 = *(const f16x8*)(&Bl[buf][(16 + rc) * 32 + sb * 8]);    \
    const f16x8 bl2 = *(const f16x8*)(&Bl[buf][(32 + rc) * 32 + sb * 8]);    \
    const f16x8 bl3 = *(const f16x8*)(&Bl[buf][(48 + rc) * 32 + sb * 8]);    \
    const f16x2 h0 = __builtin_amdgcn_cvt_pkrtz(a0.x, a0.y);                 \
    const f16x2 h1 = __builtin_amdgcn_cvt_pkrtz(a0.z, a0.w);                 \
    const f16x2 h2 = __builtin_amdgcn_cvt_pkrtz(a1.x, a1.y);                 \
    const f16x2 h3 = __builtin_amdgcn_cvt_pkrtz(a1.z, a1.w);                 \
    const f16x2 m0 = __builtin_amdgcn_cvt_pkrtz(a0.x - (float)h0[0],         \
                                                a0.y - (float)h0[1]);        \
    const f16x2 m1 = __builtin_amdgcn_cvt_pkrtz(a0.z - (float)h1[0],         \
                                                a0.w - (float)h1[1]);        \
    const f16x2 m2 = __builtin_amdgcn_cvt_pkrtz(a1.x - (float)h2[0],         \
                                                a1.y - (float)h2[1]);        \
    const f16x2 m3 = __builtin_amdgcn_cvt_pkrtz(a1.z - (float)h3[0],         \
                                                a1.w - (float)h3[1]);        \
    const f16x8 Ah = {h0[0],h0[1],h1[0],h1[1],h2[0],h2[1],h3[0],h3[1]};      \
    const f16x8 Am = {m0[0],m0[1],m1[0],m1[1],m2[0],m2[1],m3[0],m3[1]};      \
    acc0 = __builtin_amdgcn_mfma_f32_16x16x32_f16(Ah, bh0, acc0, 0, 0, 0);   \
    acc1 = __builtin_amdgcn_mfma_f32_16x16x32_f16(Ah, bh1, acc1, 0, 0, 0);   \
    acc2 = __builtin_amdgcn_mfma_f32_16x16x32_f16(Ah, bh2, acc2, 0, 0, 0);   \
    acc3 = __builtin_amdgcn_mfma_f32_16x16x32_f16(Ah, bh3, acc3, 0, 0, 0);   \
    acc0 = __builtin_amdgcn_mfma_f32_16x16x32_f16(Ah, bl0, acc0, 0, 0, 0);   \
    acc1 = __builtin_amdgcn_mfma_f32_16x16x32_f16(Ah, bl1, acc1, 0, 0, 0);   \
    acc2 = __builtin_amdgcn_mfma_f32_16x16x32_f16(Ah, bl2, acc2, 0, 0, 0);   \
    acc3 = __builtin_amdgcn_mfma_f32_16x16x32_f16(Ah, bl3, acc3, 0, 0, 0);   \
    acc0 = __builtin_amdgcn_mfma_f32_16x16x32_f16(Am, bh0, acc0, 0, 0, 0);   \
    acc1 = __builtin_amdgcn_mfma_f32_16x16x32_f16(Am, bh1, acc1, 0, 0, 0);   \
    acc2 = __builtin_amdgcn_mfma_f32_16x16x32_f16(Am, bh2, acc2, 0, 0, 0);   \
    acc3 = __builtin_amdgcn_mfma_f32_16x16x32_f16(Am, bh3, acc3, 0, 0, 0);   \
  }

  // counted-wait + collective barrier (data for chunk about to be computed
  // has landed in every wave), then compute, then barrier (buffer reuse fence)
#define STEP(buf, waitcnt_str) {                                             \
    asm volatile("s_waitcnt vmcnt(" waitcnt_str ")" ::: "memory");           \
    __builtin_amdgcn_s_barrier();                                            \
    COMP(buf);                                                               \
    __builtin_amdgcn_s_barrier();                                            \
  }

  // prologue: 2 chunks in flight
  STAGE(0, 0);
  STAGE(1, 1);

  // chunks 0..29: ten triplets; stage 2-ahead, wait keeps 8 loads in flight
  for (int i = 0; i < 10; ++i) {
    const int c = 3 * i;
    STAGE(2, c + 2);  STEP(0, "8");   // chunk c     (buf0)
    STAGE(0, c + 3);  STEP(1, "8");   // chunk c + 1 (buf1)
    STAGE(1, c + 4);  STEP(2, "8");   // chunk c + 2 (buf2)
  }
  // epilogue: chunks 30 (buf0), 31 (buf1)
  STEP(0, "4");
  asm volatile("s_waitcnt vmcnt(0)" ::: "memory");
  __builtin_amdgcn_s_barrier();
  COMP(1);

#undef STAGE
#undef COMP
#undef STEP

  // write partial logits: D row = q*4+rr (token within 16), col = 16t+rc
  float* P = partial + ((size_t)s * NTOK + wrow) * NEXP;
  #pragma unroll
  for (int rr = 0; rr < 4; ++rr) {
    const int row = q * 4 + rr;
    P[(size_t)row * NEXP +  0 + rc] = acc0[rr];
    P[(size_t)row * NEXP + 16 + rc] = acc1[rr];
    P[(size_t)row * NEXP + 32 + rc] = acc2[rr];
    P[(size_t)row * NEXP + 48 + rc] = acc3[rr];
  }
}

// ---- phase 2: reduce partials, softmax + top-2 ----
__global__ __launch_bounds__(64) void router_finish(
    const float* __restrict__ partial,
    float* __restrict__ out)
{
  const int t = blockIdx.x * 64 + threadIdx.x;

  float l[NEXP];
  const float* p0 = partial + (size_t)t * NEXP;
  #pragma unroll
  for (int qq = 0; qq < 16; ++qq) {
    const float4 v = *(const float4*)(p0 + qq * 4);
    l[qq*4+0] = v.x; l[qq*4+1] = v.y; l[qq*4+2] = v.z; l[qq*4+3] = v.w;
  }
  #pragma unroll
  for (int s = 1; s < KS; ++s) {
    const float* p = partial + ((size_t)s * NTOK + t) * NEXP;
    #pragma unroll
    for (int qq = 0; qq < 16; ++qq) {
      const float4 v = *(const float4*)(p + qq * 4);
      l[qq*4+0] += v.x; l[qq*4+1] += v.y; l[qq*4+2] += v.z; l[qq*4+3] += v.w;
    }
  }

  // top-2, lax.top_k tie-break (ascending scan with strict > keeps lower idx)
  float t1v = l[0]; int t1i = 0;
  float t2v = -INFINITY; int t2i = NEXP;
  #pragma unroll
  for (int e = 1; e < NEXP; ++e) {
    const float v = l[e];
    if (v > t1v) { t2v = t1v; t2i = t1i; t1v = v; t1i = e; }
    else if (v > t2v) { t2v = v; t2i = e; }
  }

  float ssum = 0.f;
  #pragma unroll
  for (int e = 0; e < NEXP; ++e) ssum += expf(l[e] - t1v);

  const float inv = 1.0f / ssum;
  out[t * 2 + 0] = inv;
  out[t * 2 + 1] = expf(t2v - t1v) * inv;
  out[2 * NTOK + t * 2 + 0] = (float)t1i;
  out[2 * NTOK + t * 2 + 1] = (float)t2i;
}

extern "C" void kernel_launch(void* const* d_in, const int* in_sizes, int n_in,
                              void* d_out, int out_size, void* d_ws, size_t ws_size,
                              hipStream_t stream) {
  const float* tokens = (const float*)d_in[0];
  const float* W      = (const float*)d_in[1];
  float* out          = (float*)d_out;

  __fp16* Wh = (__fp16*)d_ws;
  __fp16* Wl = Wh + (size_t)NEXP * DIM;
  float* partial = (float*)((char*)d_ws + (size_t)2 * NEXP * DIM * sizeof(__fp16));

  split_w<<<(NEXP * DIM) / 256, 256, 0, stream>>>(W, Wh, Wl);
  router_mfma<<<(NTOK / BM) * KS, 256, 0, stream>>>(tokens, Wh, Wl, partial);
  router_finish<<<NTOK / 64, 64, 0, stream>>>(partial, out);
}

// Round 9
// 77.263 us; speedup vs baseline: 1.1965x; 1.1965x over previous
//
#include <hip/hip_runtime.h>
#include <math.h>

#define NTOK 16384
#define DIM  4096
#define NEXP 64
#define KS   4                // K-split factor
#define KSL  (DIM / KS)       // 1024 k per slice
#define NCH  (KSL / 32)       // 32 chunks of 32 per slice
#define BM   128              // tokens per block (4 waves x 32)

typedef __fp16 f16x8 __attribute__((ext_vector_type(8)));
typedef __fp16 f16x2 __attribute__((ext_vector_type(2)));
typedef float  f32x4 __attribute__((ext_vector_type(4)));

__device__ __forceinline__ void gl_lds16(const void* g, void* l) {
  __builtin_amdgcn_global_load_lds(
      (const __attribute__((address_space(1))) void*)g,
      (__attribute__((address_space(3))) void*)l, 16, 0, 0);
}

// ---- prep: split W (fp32) into 2 fp16 planes (RNE hi, RNE residual) ----
__global__ __launch_bounds__(256) void split_w(
    const float* __restrict__ W,
    __fp16* __restrict__ Wh,
    __fp16* __restrict__ Wl)
{
  const int i = blockIdx.x * 256 + threadIdx.x;   // grid covers 64*4096
  const float w = W[i];
  const __fp16 h = (__fp16)w;                     // RNE
  const float r = w - (float)h;                   // exact
  Wh[i] = h;
  Wl[i] = (__fp16)r;                              // RNE, residual ~2^-24|w|
}

// ---- phase 1: partial logits; BM=128, gl_lds double-buffer (r7 sync) ----
__global__ __launch_bounds__(256, 2) void router_mfma(
    const float* __restrict__ tokens,
    const __fp16* __restrict__ Wh,
    const __fp16* __restrict__ Wl,
    float* __restrict__ partial)   // [KS][NTOK][NEXP]
{
  __shared__ float  As[2][BM * 32];     // 2 x 16 KB
  __shared__ __fp16 Bh[2][NEXP * 32];   // 2 x 4 KB
  __shared__ __fp16 Bl[2][NEXP * 32];   // 2 x 4 KB   -> 48 KB

  const int tid  = threadIdx.x;
  const int wid  = tid >> 6;
  const int lane = tid & 63;
  const int rc   = lane & 15;           // A-row / B-col within 16
  const int q    = lane >> 4;           // k-group (0..3)
  const int s    = blockIdx.x & (KS - 1);
  const int rowbase = (blockIdx.x >> 2) * BM;     // block token base
  const int wrow    = rowbase + 32 * wid;         // this wave's 32 tokens
  const int kbase   = s * KSL;

  // ---- staging sources (pre-swizzled global addr, linear LDS dest) ----
  // A: wave stages its own 32 rows as 4 instrs x 8 rows (128B/row).
  // row-within-8 = lane>>3, quad j = lane&7, src quad = j ^ (row&7)
  const int a_tl = lane >> 3, a_j = lane & 7;
  const float* asrc = tokens + (size_t)(wrow + a_tl) * DIM + kbase
                      + ((a_j ^ a_tl) << 2);
  // B: wave stages experts 16*wid..16*wid+15 per plane (1 instr each).
  const int b_el = lane >> 2, b_j = lane & 3;
  const size_t boff = (size_t)(16 * wid + b_el) * DIM + kbase
                      + ((b_j ^ (b_el & 3)) << 3);
  const __fp16* bsrc_h = Wh + boff;
  const __fp16* bsrc_l = Wl + boff;

#define STAGE(buf, c) {                                          \
    const int ko = (c) * 32;                                     \
    gl_lds16(asrc + ko,                &As[buf][(32*wid     ) * 32]); \
    gl_lds16(asrc + (size_t) 8*DIM + ko, &As[buf][(32*wid +  8) * 32]); \
    gl_lds16(asrc + (size_t)16*DIM + ko, &As[buf][(32*wid + 16) * 32]); \
    gl_lds16(asrc + (size_t)24*DIM + ko, &As[buf][(32*wid + 24) * 32]); \
    gl_lds16(bsrc_h + ko, &Bh[buf][(16 * wid) * 32]);            \
    gl_lds16(bsrc_l + ko, &Bl[buf][(16 * wid) * 32]);            \
  }

  f32x4 accX0 = {0,0,0,0}, accX1 = {0,0,0,0}, accX2 = {0,0,0,0}, accX3 = {0,0,0,0};
  f32x4 accY0 = {0,0,0,0}, accY1 = {0,0,0,0}, accY2 = {0,0,0,0}, accY3 = {0,0,0,0};

  // read-side swizzled slots (constant per thread)
  const int sa0 = (2 * q) ^ (rc & 7), sa1 = (2 * q + 1) ^ (rc & 7);
  const int sb  = q ^ (rc & 3);
  const int arowX = (32 * wid + rc) * 32;
  const int arowY = (32 * wid + 16 + rc) * 32;

  // f32x8 (two float4) -> two fp16 planes with consistent slot->k map
#define SPLIT(a0, a1, Ah, Am) \
    const f16x2 Ah##h0 = __builtin_amdgcn_cvt_pkrtz(a0.x, a0.y);             \
    const f16x2 Ah##h1 = __builtin_amdgcn_cvt_pkrtz(a0.z, a0.w);             \
    const f16x2 Ah##h2 = __builtin_amdgcn_cvt_pkrtz(a1.x, a1.y);             \
    const f16x2 Ah##h3 = __builtin_amdgcn_cvt_pkrtz(a1.z, a1.w);             \
    const f16x2 Ah##m0 = __builtin_amdgcn_cvt_pkrtz(a0.x - (float)Ah##h0[0], \
                                                    a0.y - (float)Ah##h0[1]);\
    const f16x2 Ah##m1 = __builtin_amdgcn_cvt_pkrtz(a0.z - (float)Ah##h1[0], \
                                                    a0.w - (float)Ah##h1[1]);\
    const f16x2 Ah##m2 = __builtin_amdgcn_cvt_pkrtz(a1.x - (float)Ah##h2[0], \
                                                    a1.y - (float)Ah##h2[1]);\
    const f16x2 Ah##m3 = __builtin_amdgcn_cvt_pkrtz(a1.z - (float)Ah##h3[0], \
                                                    a1.w - (float)Ah##h3[1]);\
    const f16x8 Ah = {Ah##h0[0],Ah##h0[1],Ah##h1[0],Ah##h1[1],               \
                      Ah##h2[0],Ah##h2[1],Ah##h3[0],Ah##h3[1]};              \
    const f16x8 Am = {Ah##m0[0],Ah##m0[1],Ah##m1[0],Ah##m1[1],               \
                      Ah##m2[0],Ah##m2[1],Ah##m3[0],Ah##m3[1]};

#define MFMA3(Ah, Am, acc, bh, bl)                                           \
    acc = __builtin_amdgcn_mfma_f32_16x16x32_f16(Ah, bh, acc, 0, 0, 0);      \
    acc = __builtin_amdgcn_mfma_f32_16x16x32_f16(Ah, bl, acc, 0, 0, 0);      \
    acc = __builtin_amdgcn_mfma_f32_16x16x32_f16(Am, bh, acc, 0, 0, 0);

#define COMP(buf) {                                                          \
    const float4 x0 = *(const float4*)(&As[buf][arowX + sa0 * 4]);           \
    const float4 x1 = *(const float4*)(&As[buf][arowX + sa1 * 4]);           \
    const float4 y0 = *(const float4*)(&As[buf][arowY + sa0 * 4]);           \
    const float4 y1 = *(const float4*)(&As[buf][arowY + sa1 * 4]);           \
    const f16x8 bh0 = *(const f16x8*)(&Bh[buf][( 0 + rc) * 32 + sb * 8]);    \
    const f16x8 bh1 = *(const f16x8*)(&Bh[buf][(16 + rc) * 32 + sb * 8]);    \
    const f16x8 bh2 = *(const f16x8*)(&Bh[buf][(32 + rc) * 32 + sb * 8]);    \
    const f16x8 bh3 = *(const f16x8*)(&Bh[buf][(48 + rc) * 32 + sb * 8]);    \
    const f16x8 bl0 = *(const f16x8*)(&Bl[buf][( 0 + rc) * 32 + sb * 8]);    \
    const f16x8 bl1 = *(const f16x8*)(&Bl[buf][(16 + rc) * 32 + sb * 8]);    \
    const f16x8 bl2 = *(const f16x8*)(&Bl[buf][(32 + rc) * 32 + sb * 8]);    \
    const f16x8 bl3 = *(const f16x8*)(&Bl[buf][(48 + rc) * 32 + sb * 8]);    \
    SPLIT(x0, x1, AhX, AmX);                                                 \
    SPLIT(y0, y1, AhY, AmY);                                                 \
    MFMA3(AhX, AmX, accX0, bh0, bl0);                                        \
    MFMA3(AhX, AmX, accX1, bh1, bl1);                                        \
    MFMA3(AhX, AmX, accX2, bh2, bl2);                                        \
    MFMA3(AhX, AmX, accX3, bh3, bl3);                                        \
    MFMA3(AhY, AmY, accY0, bh0, bl0);                                        \
    MFMA3(AhY, AmY, accY1, bh1, bl1);                                        \
    MFMA3(AhY, AmY, accY2, bh2, bl2);                                        \
    MFMA3(AhY, AmY, accY3, bh3, bl3);                                        \
  }

  // prologue
  STAGE(0, 0);
  __syncthreads();

  // main loop: proven round-7 sync structure (1 barrier per chunk)
  for (int c = 0; c < NCH; c += 2) {
    if (c + 1 < NCH) STAGE(1, c + 1);
    COMP(0);
    __syncthreads();
    if (c + 2 < NCH) STAGE(0, c + 2);
    COMP(1);
    __syncthreads();
  }
#undef STAGE
#undef COMP
#undef MFMA3
#undef SPLIT

  // write partial logits: D row = q*4+rr, token = wrow + 16*tile + row
  float* P = partial + ((size_t)s * NTOK + wrow) * NEXP;
  #pragma unroll
  for (int rr = 0; rr < 4; ++rr) {
    const int rowX = q * 4 + rr;
    P[(size_t)rowX * NEXP +  0 + rc] = accX0[rr];
    P[(size_t)rowX * NEXP + 16 + rc] = accX1[rr];
    P[(size_t)rowX * NEXP + 32 + rc] = accX2[rr];
    P[(size_t)rowX * NEXP + 48 + rc] = accX3[rr];
    const int rowY = 16 + q * 4 + rr;
    P[(size_t)rowY * NEXP +  0 + rc] = accY0[rr];
    P[(size_t)rowY * NEXP + 16 + rc] = accY1[rr];
    P[(size_t)rowY * NEXP + 32 + rc] = accY2[rr];
    P[(size_t)rowY * NEXP + 48 + rc] = accY3[rr];
  }
}

// ---- phase 2: reduce partials, softmax + top-2 ----
__global__ __launch_bounds__(64) void router_finish(
    const float* __restrict__ partial,
    float* __restrict__ out)
{
  const int t = blockIdx.x * 64 + threadIdx.x;

  float l[NEXP];
  const float* p0 = partial + (size_t)t * NEXP;
  #pragma unroll
  for (int qq = 0; qq < 16; ++qq) {
    const float4 v = *(const float4*)(p0 + qq * 4);
    l[qq*4+0] = v.x; l[qq*4+1] = v.y; l[qq*4+2] = v.z; l[qq*4+3] = v.w;
  }
  #pragma unroll
  for (int s = 1; s < KS; ++s) {
    const float* p = partial + ((size_t)s * NTOK + t) * NEXP;
    #pragma unroll
    for (int qq = 0; qq < 16; ++qq) {
      const float4 v = *(const float4*)(p + qq * 4);
      l[qq*4+0] += v.x; l[qq*4+1] += v.y; l[qq*4+2] += v.z; l[qq*4+3] += v.w;
    }
  }

  // top-2, lax.top_k tie-break (ascending scan with strict > keeps lower idx)
  float t1v = l[0]; int t1i = 0;
  float t2v = -INFINITY; int t2i = NEXP;
  #pragma unroll
  for (int e = 1; e < NEXP; ++e) {
    const float v = l[e];
    if (v > t1v) { t2v = t1v; t2i = t1i; t1v = v; t1i = e; }
    else if (v > t2v) { t2v = v; t2i = e; }
  }

  float ssum = 0.f;
  #pragma unroll
  for (int e = 0; e < NEXP; ++e) ssum += expf(l[e] - t1v);

  const float inv = 1.0f / ssum;
  out[t * 2 + 0] = inv;
  out[t * 2 + 1] = expf(t2v - t1v) * inv;
  out[2 * NTOK + t * 2 + 0] = (float)t1i;
  out[2 * NTOK + t * 2 + 1] = (float)t2i;
}

extern "C" void kernel_launch(void* const* d_in, const int* in_sizes, int n_in,
                              void* d_out, int out_size, void* d_ws, size_t ws_size,
                              hipStream_t stream) {
  const float* tokens = (const float*)d_in[0];
  const float* W      = (const float*)d_in[1];
  float* out          = (float*)d_out;

  __fp16* Wh = (__fp16*)d_ws;
  __fp16* Wl = Wh + (size_t)NEXP * DIM;
  float* partial = (float*)((char*)d_ws + (size_t)2 * NEXP * DIM * sizeof(__fp16));

  split_w<<<(NEXP * DIM) / 256, 256, 0, stream>>>(W, Wh, Wl);
  router_mfma<<<(NTOK / BM) * KS, 256, 0, stream>>>(tokens, Wh, Wl, partial);
  router_finish<<<NTOK / 64, 64, 0, stream>>>(partial, out);
}